// Round 2
// baseline (61919.391 us; speedup 1.0000x reference)
//
#include <hip/hip_runtime.h>
#include <hip/hip_fp16.h>

#define TLEN 16384
#define HD 128
#define NG 384

// ---------------------------------------------------------------------------
// Sequential GRU scan: 4 independent chains (one per channel — NOTE the
// reference's stack().transpose(0,2,1) makes "batch" = channel and
// "feature" = original batch row). 1 block per chain.
// Thread t: k = t>>1 (gate-row 0..383), half = t&1 (j-range half*64..+63).
// Weights held in VGPRs; h in LDS; 2 barriers per step.
// ---------------------------------------------------------------------------
__global__ __launch_bounds__(768) void gru_kernel(
    const float* __restrict__ px,
    const float* __restrict__ py,
    const float* __restrict__ vx,
    const float* __restrict__ vy,
    const float* __restrict__ Wemb,   // [128,4]
    const float* __restrict__ bemb,   // [128]
    const float* __restrict__ Wih,    // [384,128]
    const float* __restrict__ Whh,    // [384,128]
    const float* __restrict__ bih,    // [384]
    const float* __restrict__ bhh,    // [384]
    const int*   __restrict__ step_mask, // [16384]
    const int*   __restrict__ ctxp,      // [1]
    __half*      __restrict__ hs)        // [4*16384*128] f16 staging
{
    const int bb  = blockIdx.x;   // chain == channel
    const float* xsrc = (bb == 0) ? px : (bb == 1) ? py : (bb == 2) ? vx : vy;
    const int tid  = threadIdx.x;
    const int k    = tid >> 1;
    const int half = tid & 1;
    const int jb   = half << 6;   // 0 or 64

    __shared__ float hbuf[HD];
    __shared__ float gigh[2 * NG];     // interleaved (gi, gh) per gate-row k
    __shared__ float xbuf[256 * 4];    // prefetched x features (feature = orig batch row)
    __shared__ int   uxbuf[256];       // prefetched use_x flags
    __shared__ float WembL[HD * 4];
    __shared__ float bembL[HD];

    // ---- one-time: this thread's weight half-rows into registers
    float wh[64], wi[64];
    {
        const float4* p = (const float4*)(Whh + k * HD + jb);
        const float4* q = (const float4*)(Wih + k * HD + jb);
        #pragma unroll
        for (int c = 0; c < 16; ++c) {
            float4 a = p[c];
            wh[c*4+0] = a.x; wh[c*4+1] = a.y; wh[c*4+2] = a.z; wh[c*4+3] = a.w;
            float4 b = q[c];
            wi[c*4+0] = b.x; wi[c*4+1] = b.y; wi[c*4+2] = b.z; wi[c*4+3] = b.w;
        }
    }
    if (tid < 512)                WembL[tid]       = Wemb[tid];
    if (tid >= 512 && tid < 640)  bembL[tid - 512] = bemb[tid - 512];
    if (tid < HD)                 hbuf[tid]        = 0.f;
    __syncthreads();

    // ---- fold embed into x-path: Wc[k][f] = sum_j Wih[k][j]*Wemb[j][f]
    const float bihv = bih[k];
    const float bhhv = bhh[k];
    float wc0 = 0.f, wc1 = 0.f, wc2 = 0.f, wc3 = 0.f, bcp = 0.f;
    #pragma unroll
    for (int j = 0; j < 64; ++j) {
        const float w = wi[j];
        const float4 e = *(const float4*)&WembL[(jb + j) * 4];
        wc0 = fmaf(w, e.x, wc0); wc1 = fmaf(w, e.y, wc1);
        wc2 = fmaf(w, e.z, wc2); wc3 = fmaf(w, e.w, wc3);
        bcp = fmaf(w, bembL[jb + j], bcp);
    }
    wc0 += __shfl_xor(wc0, 1, 64); wc1 += __shfl_xor(wc1, 1, 64);
    wc2 += __shfl_xor(wc2, 1, 64); wc3 += __shfl_xor(wc3, 1, 64);
    bcp += __shfl_xor(bcp, 1, 64);
    const float bc   = bihv + bcp;
    const int   ctxm = (ctxp[0] < 1) ? 1 : ctxp[0];

    for (int t0 = 0; t0 < TLEN; t0 += 256) {
        // prefetch x + use_x (prev step's trailing barrier protects xbuf)
        if (tid < 256) {
            const int gt = t0 + tid;
            xbuf[tid*4+0] = xsrc[0*TLEN + gt];
            xbuf[tid*4+1] = xsrc[1*TLEN + gt];
            xbuf[tid*4+2] = xsrc[2*TLEN + gt];
            xbuf[tid*4+3] = xsrc[3*TLEN + gt];
            uxbuf[tid] = ((gt < ctxm) || (step_mask[gt] == 0)) ? 1 : 0;
        }
        __syncthreads();
        for (int tt = 0; tt < 256; ++tt) {
            const int ux = __builtin_amdgcn_readfirstlane(uxbuf[tt]);
            float agh = 0.f, agi = 0.f;
            if (ux) {
                #pragma unroll
                for (int c = 0; c < 16; ++c) {
                    const float4 h4 = *(const float4*)&hbuf[jb + c*4];
                    agh = fmaf(wh[c*4+0], h4.x, agh);
                    agh = fmaf(wh[c*4+1], h4.y, agh);
                    agh = fmaf(wh[c*4+2], h4.z, agh);
                    agh = fmaf(wh[c*4+3], h4.w, agh);
                }
            } else {
                #pragma unroll
                for (int c = 0; c < 16; ++c) {
                    const float4 h4 = *(const float4*)&hbuf[jb + c*4];
                    agh = fmaf(wh[c*4+0], h4.x, agh); agi = fmaf(wi[c*4+0], h4.x, agi);
                    agh = fmaf(wh[c*4+1], h4.y, agh); agi = fmaf(wi[c*4+1], h4.y, agi);
                    agh = fmaf(wh[c*4+2], h4.z, agh); agi = fmaf(wi[c*4+2], h4.z, agi);
                    agh = fmaf(wh[c*4+3], h4.w, agh); agi = fmaf(wi[c*4+3], h4.w, agi);
                }
            }
            agh += __shfl_xor(agh, 1, 64);
            agi += __shfl_xor(agi, 1, 64);
            if (half == 0) {
                const float gh = agh + bhhv;
                float gi;
                if (ux) {
                    const float4 xv = *(const float4*)&xbuf[tt*4];
                    gi = bc;
                    gi = fmaf(wc0, xv.x, gi); gi = fmaf(wc1, xv.y, gi);
                    gi = fmaf(wc2, xv.z, gi); gi = fmaf(wc3, xv.w, gi);
                } else {
                    gi = agi + bihv;
                }
                *(float2*)&gigh[2*k] = make_float2(gi, gh);
            }
            __syncthreads();
            // gates + state update (PyTorch GRUCell: r,z,n order)
            if (tid < HD) {
                const float2 gr = *(const float2*)&gigh[2*tid];
                const float2 gz = *(const float2*)&gigh[2*(HD + tid)];
                const float2 gn = *(const float2*)&gigh[2*(2*HD + tid)];
                const float r    = 1.f / (1.f + __expf(-(gr.x + gr.y)));
                const float z    = 1.f / (1.f + __expf(-(gz.x + gz.y)));
                const float npre = fmaf(r, gn.y, gn.x);
                const float e2   = __expf(2.f * npre);
                const float n    = 1.f - 2.f / (e2 + 1.f);       // tanh(npre)
                const float hold = hbuf[tid];
                const float hnew = fmaf(z, hold - n, n);         // (1-z)*n + z*h
                hbuf[tid] = hnew;
                hs[((size_t)(bb * TLEN + t0 + tt)) * HD + tid] = __float2half(hnew);
            }
            __syncthreads();
        }
    }
}

// ---------------------------------------------------------------------------
// Head MLP over all 65536 hidden states: thread-per-row, weights uniform in
// LDS (broadcast reads), h in registers, y1 in padded LDS (stride 65 => no
// bank conflicts).
// ---------------------------------------------------------------------------
__global__ __launch_bounds__(64) void head_kernel(
    const float*  __restrict__ W1,  // [64,128]
    const float*  __restrict__ b1,  // [64]
    const float*  __restrict__ W2,  // [64,64]
    const float*  __restrict__ b2,  // [64]
    const float*  __restrict__ W3,  // [2,64]
    const float*  __restrict__ b3,  // [2]
    const __half* __restrict__ hs,
    float*        __restrict__ out)
{
    __shared__ float W1L[64 * 128];
    __shared__ float W2L[64 * 64];
    __shared__ float W3L[2 * 64];
    __shared__ float b1L[64], b2L[64], b3L[2];
    __shared__ float y1L[64 * 65];   // per-thread row, stride 65 (bank pad)

    const int tid = threadIdx.x;
    {
        float4* dst1 = (float4*)W1L; const float4* src1 = (const float4*)W1;
        for (int i = tid; i < 2048; i += 64) dst1[i] = src1[i];
        float4* dst2 = (float4*)W2L; const float4* src2 = (const float4*)W2;
        for (int i = tid; i < 1024; i += 64) dst2[i] = src2[i];
        if (tid < 32) ((float4*)W3L)[tid] = ((const float4*)W3)[tid];
        b1L[tid] = b1[tid];
        b2L[tid] = b2[tid];
        if (tid < 2) b3L[tid] = b3[tid];
    }
    __syncthreads();

    const int row = blockIdx.x * 64 + tid;   // row = bb*16384 + t
    float h[128];
    {
        const uint4* hp = (const uint4*)(hs + (size_t)row * HD);
        #pragma unroll
        for (int c = 0; c < 16; ++c) {
            uint4 q = hp[c];
            const __half2* hh = (const __half2*)&q;
            #pragma unroll
            for (int d = 0; d < 4; ++d) {
                const float2 f = __half22float2(hh[d]);
                h[c*8 + d*2 + 0] = f.x;
                h[c*8 + d*2 + 1] = f.y;
            }
        }
    }
    // layer 1: y1 = elu(W1 h + b1)
    for (int l = 0; l < 64; ++l) {
        float a0 = b1L[l], a1 = 0.f;
        #pragma unroll
        for (int j = 0; j < 128; j += 4) {
            const float4 w = *(const float4*)&W1L[l*128 + j];
            a0 = fmaf(w.x, h[j+0], a0);
            a1 = fmaf(w.y, h[j+1], a1);
            a0 = fmaf(w.z, h[j+2], a0);
            a1 = fmaf(w.w, h[j+3], a1);
        }
        const float acc = a0 + a1;
        y1L[tid * 65 + l] = (acc > 0.f) ? acc : (__expf(acc) - 1.f);
    }
    // layer 2 + layer 3 fused: y3 += W3 * elu(W2 y1 + b2)
    float y30 = b3L[0], y31 = b3L[1];
    for (int l = 0; l < 64; ++l) {
        float a0 = b2L[l], a1 = 0.f;
        const int yb = tid * 65;
        #pragma unroll
        for (int j = 0; j < 64; j += 4) {
            const float4 w = *(const float4*)&W2L[l*64 + j];
            a0 = fmaf(w.x, y1L[yb + j+0], a0);
            a1 = fmaf(w.y, y1L[yb + j+1], a1);
            a0 = fmaf(w.z, y1L[yb + j+2], a0);
            a1 = fmaf(w.w, y1L[yb + j+3], a1);
        }
        const float acc = a0 + a1;
        const float v = (acc > 0.f) ? acc : (__expf(acc) - 1.f);
        y30 = fmaf(W3L[l],      v, y30);
        y31 = fmaf(W3L[64 + l], v, y31);
    }
    out[row]            = y30;
    out[4 * TLEN + row] = y31;
}

extern "C" void kernel_launch(void* const* d_in, const int* in_sizes, int n_in,
                              void* d_out, int out_size, void* d_ws, size_t ws_size,
                              hipStream_t stream) {
    const float* px   = (const float*)d_in[0];
    const float* py   = (const float*)d_in[1];
    const float* vx   = (const float*)d_in[2];
    const float* vy   = (const float*)d_in[3];
    const float* Wemb = (const float*)d_in[4];
    const float* bemb = (const float*)d_in[5];
    const float* Wih  = (const float*)d_in[6];
    const float* Whh  = (const float*)d_in[7];
    const float* bih  = (const float*)d_in[8];
    const float* bhh  = (const float*)d_in[9];
    const float* W1   = (const float*)d_in[10];
    const float* b1   = (const float*)d_in[11];
    const float* W2   = (const float*)d_in[12];
    const float* b2   = (const float*)d_in[13];
    const float* W3   = (const float*)d_in[14];
    const float* b3   = (const float*)d_in[15];
    const int* step_mask = (const int*)d_in[16];
    const int* ctx       = (const int*)d_in[17];
    __half* hs = (__half*)d_ws;          // 4*16384*128 f16 = 16.8 MB
    float* out = (float*)d_out;          // f32, [2][4][16384] flat

    hipLaunchKernelGGL(gru_kernel, dim3(4), dim3(768), 0, stream,
                       px, py, vx, vy, Wemb, bemb, Wih, Whh, bih, bhh,
                       step_mask, ctx, hs);
    hipLaunchKernelGGL(head_kernel, dim3(1024), dim3(64), 0, stream,
                       W1, b1, W2, b2, W3, b3, hs, out);
}